// Round 18
// baseline (93.030 us; speedup 1.0000x reference)
//
#include <hip/hip_runtime.h>
#include <math.h>

#define NQ     4
#define IMGD   28
#define HP     14          // patches per spatial dim
#define NPATCH 196         // 14*14
#define BATCH  2048
#define FEAT   784         // 196*4
#define HID    20
#define NCLS   2

// ---------------------------------------------------------------------------
// DIAGNOSTIC ROUND: kernel body identical to round 17 (passed, 79.9 us).
// Grid doubled to 4096 with b = blockIdx >> 1 (block pairs duplicate one
// image; identical redundant out-writes). Purpose: push the dispatch to
// ~50 us so it beats the five ~41 us ws-poison fills into rocprof top-5,
// exposing VGPR/VALUBusy/Occupancy/FETCH for the real workload. The stall
// model has been 2-3x off three times (r3/r16/r17); buying counters.
// ---------------------------------------------------------------------------

// CRZ ring composed phase integer k(b) = sum_i b_i*(2*b_{(i+1)%4}-1),
// idx = b0*8+b1*4+b2*2+b3 (wire0 = MSB). k = {0,-1,-1,0,-1,-2,0,1,-1,0,-2,1,0,1,1,4}
// k=0 at idx 0,3,6,9,12 -> identity phase (hard-coded below).

// RY 2x2 rotation on amplitude pair (i, j=i|m), complex state
#define RYP(i,j)                                                    \
    { const float t0r = cr##i, t1r = cr##j;                         \
      const float t0i = ci##i, t1i = ci##j;                         \
      cr##i = cy * t0r - sy * t1r;  cr##j = sy * t0r + cy * t1r;    \
      ci##i = cy * t0i - sy * t1i;  ci##j = sy * t0i + cy * t1i; }

#define RY_LAYER()                                                  \
    /* wire 0 (m=8) */ RYP(0,8)  RYP(1,9)  RYP(2,10) RYP(3,11)     \
                       RYP(4,12) RYP(5,13) RYP(6,14) RYP(7,15)     \
    /* wire 1 (m=4) */ RYP(0,4)  RYP(1,5)  RYP(2,6)  RYP(3,7)      \
                       RYP(8,12) RYP(9,13) RYP(10,14) RYP(11,15)   \
    /* wire 2 (m=2) */ RYP(0,2)  RYP(1,3)  RYP(4,6)  RYP(5,7)      \
                       RYP(8,10) RYP(9,11) RYP(12,14) RYP(13,15)   \
    /* wire 3 (m=1) */ RYP(0,1)  RYP(2,3)  RYP(4,5)  RYP(6,7)      \
                       RYP(8,9)  RYP(10,11) RYP(12,13) RYP(14,15)

// full complex diagonal phase multiply: (cr,ci) *= (c_ + i*s_)
#define CRZC(i, c_, s_)                                             \
    { const float nr = cr##i * (c_) - ci##i * (s_);                 \
      ci##i = cr##i * (s_) + ci##i * (c_);  cr##i = nr; }

__global__ __launch_bounds__(256) void fused_qnn_kernel(
    const float* __restrict__ x,         // [2048,1,28,28]
    const float* __restrict__ ry_theta,  // [1]
    const float* __restrict__ crz_theta, // [1]
    const float* __restrict__ fc1_w,     // [20,784]
    const float* __restrict__ fc1_b,     // [20]
    const float* __restrict__ fc2_w,     // [2,20]
    const float* __restrict__ fc2_b,     // [2]
    float* __restrict__ out)             // [2048,2]
{
    __shared__ float zs[FEAT];
    __shared__ float hid_s[HID];

    const int tid = threadIdx.x;
    const int b   = blockIdx.x >> 1;     // DIAG: pairs (2i,2i+1) -> image i

    // ---- Phase 0: uniform trig, per-thread in-register ----
    const float hcrz = 0.5f * crz_theta[0];
    const float c1 = __cosf(hcrz), s1 = __sinf(hcrz);
    const float c2 = c1 * c1 - s1 * s1, s2 = 2.f * c1 * s1;
    const float c4 = c2 * c2 - s2 * s2, s4 = 2.f * c2 * s2;
    const float hry = 0.5f * ry_theta[0];
    const float cy = __cosf(hry), sy = __sinf(hry);

    // ---- Phase 1: circuit for one patch per thread (tid < 196) ----
    if (tid < NPATCH) {
        const int ph = tid / HP, pw = tid - ph * HP;
        const float* xb = x + (size_t)b * (IMGD * IMGD);
        const float2 p0 = *(const float2*)(xb + (2 * ph)     * IMGD + 2 * pw);
        const float2 p1 = *(const float2*)(xb + (2 * ph + 1) * IMGD + 2 * pw);

        const float h0 = 0.5f * p0.x, h1 = 0.5f * p0.y;
        const float h2 = 0.5f * p1.x, h3 = 0.5f * p1.y;
        const float A0 = __cosf(h0), S0  = __sinf(h0);
        const float A1 = __cosf(h1), S1v = __sinf(h1);
        const float A2 = __cosf(h2), S2v = __sinf(h2);
        const float A3 = __cosf(h3), S3v = __sinf(h3);

        // Encoder product state via shared partials (24 mul)
        const float q00 = A0 * A1,  q01 = A0 * S1v, q10 = S0 * A1,  q11 = S0 * S1v;
        const float r00 = A2 * A3,  r01 = A2 * S3v, r10 = S2v * A3, r11 = S2v * S3v;
        float cr0  = q00 * r00, cr1  = q00 * r01, cr2  = q00 * r10, cr3  = q00 * r11;
        float cr4  = q01 * r00, cr5  = q01 * r01, cr6  = q01 * r10, cr7  = q01 * r11;
        float cr8  = q10 * r00, cr9  = q10 * r01, cr10 = q10 * r10, cr11 = q10 * r11;
        float cr12 = q11 * r00, cr13 = q11 * r01, cr14 = q11 * r10, cr15 = q11 * r11;

        // layer 0 CRZ on real state: ci = cr*sin, cr *= cos (k=0 -> identity)
        float ci0 = 0.f, ci3 = 0.f, ci6 = 0.f, ci9 = 0.f, ci12 = 0.f;
        float ci1  = -cr1  * s1;  cr1  *= c1;   // k=-1
        float ci2  = -cr2  * s1;  cr2  *= c1;   // k=-1
        float ci4  = -cr4  * s1;  cr4  *= c1;   // k=-1
        float ci5  = -cr5  * s2;  cr5  *= c2;   // k=-2
        float ci7  =  cr7  * s1;  cr7  *= c1;   // k=+1
        float ci8  = -cr8  * s1;  cr8  *= c1;   // k=-1
        float ci10 = -cr10 * s2;  cr10 *= c2;   // k=-2
        float ci11 =  cr11 * s1;  cr11 *= c1;   // k=+1
        float ci13 =  cr13 * s1;  cr13 *= c1;   // k=+1
        float ci14 =  cr14 * s1;  cr14 *= c1;   // k=+1
        float ci15 =  cr15 * s4;  cr15 *= c4;   // k=+4

        RY_LAYER()

        // layer 1 CRZ, full complex (skip k=0 indices)
        CRZC(1,  c1, -s1)  CRZC(2,  c1, -s1)  CRZC(4,  c1, -s1)  CRZC(8,  c1, -s1)
        CRZC(5,  c2, -s2)  CRZC(10, c2, -s2)
        CRZC(7,  c1,  s1)  CRZC(11, c1,  s1)  CRZC(13, c1,  s1)  CRZC(14, c1,  s1)
        CRZC(15, c4,  s4)

        RY_LAYER()

        // probabilities + PauliZ sums via shared sum/diff tree
#define PROB(i) const float pp##i = cr##i * cr##i + ci##i * ci##i;
        PROB(0) PROB(1) PROB(2) PROB(3) PROB(4) PROB(5) PROB(6) PROB(7)
        PROB(8) PROB(9) PROB(10) PROB(11) PROB(12) PROB(13) PROB(14) PROB(15)
#undef PROB
        const float t01 = pp0 + pp1,   t23 = pp2 + pp3;
        const float t45 = pp4 + pp5,   t67 = pp6 + pp7;
        const float t89 = pp8 + pp9,   tab = pp10 + pp11;
        const float tcd = pp12 + pp13, tef = pp14 + pp15;
        const float u0 = t01 + t23, u1 = t45 + t67, u2 = t89 + tab, u3 = tcd + tef;
        const float z0 = (u0 + u1) - (u2 + u3);                       // wire0
        const float z1 = (u0 + u2) - (u1 + u3);                       // wire1
        const float z2 = (t01 - t23) + (t45 - t67) + (t89 - tab) + (tcd - tef);
        const float z3 = ((pp0 - pp1) + (pp2 - pp3)) + ((pp4 - pp5) + (pp6 - pp7))
                       + ((pp8 - pp9) + (pp10 - pp11)) + ((pp12 - pp13) + (pp14 - pp15));

        *((float4*)&zs[tid * 4]) = make_float4(z0, z1, z2, z3);
    }
    __syncthreads();

    // ---- Phase 2: FC1, 16 groups x 16 lanes, 2 passes ----
    const int g = tid >> 4;          // 0..15
    const int l = tid & 15;          // lane within group
    const float4* z4 = (const float4*)zs;

    #pragma unroll
    for (int pass = 0; pass < 2; ++pass) {
        const int h = (pass == 0) ? g : (16 + g);
        if (pass == 1 && g >= 4) break;           // tid>=64: whole waves 1-3 exit
        const float* wrow = fc1_w + h * FEAT;
        const float4* w4 = (const float4*)wrow;

        float4 a4 = make_float4(0.f, 0.f, 0.f, 0.f);
        #pragma unroll
        for (int i = 0; i < 12; ++i) {            // 12*16 float4 = 768 floats
            const int f4 = l + (i << 4);
            const float4 zz = z4[f4];
            const float4 ww = w4[f4];
            a4.x += zz.x * ww.x;  a4.y += zz.y * ww.y;
            a4.z += zz.z * ww.z;  a4.w += zz.w * ww.w;
        }
        float acc = (a4.x + a4.y) + (a4.z + a4.w);
        acc += zs[768 + l] * wrow[768 + l];       // 16-float tail

        acc += __shfl_xor(acc, 1, 16);
        acc += __shfl_xor(acc, 2, 16);
        acc += __shfl_xor(acc, 4, 16);
        acc += __shfl_xor(acc, 8, 16);
        if (l == 0) hid_s[h] = acc + fc1_b[h];
    }
    __syncthreads();

    // ---- Phase 3: ReLU + FC2 (duplicate blocks write identical values) ----
    if (tid < NCLS) {
        float o = fc2_b[tid];
        #pragma unroll
        for (int h = 0; h < HID; ++h)
            o += fmaxf(hid_s[h], 0.f) * fc2_w[tid * HID + h];
        out[b * NCLS + tid] = o;
    }
}

extern "C" void kernel_launch(void* const* d_in, const int* in_sizes, int n_in,
                              void* d_out, int out_size, void* d_ws, size_t ws_size,
                              hipStream_t stream) {
    const float* x         = (const float*)d_in[0];
    const float* ry_theta  = (const float*)d_in[1];
    const float* crz_theta = (const float*)d_in[2];
    const float* fc1_w     = (const float*)d_in[3];
    const float* fc1_b     = (const float*)d_in[4];
    const float* fc2_w     = (const float*)d_in[5];
    const float* fc2_b     = (const float*)d_in[6];
    float* out = (float*)d_out;

    // DIAG: 2x grid (duplicate-image pairs) to exceed the ~41 us fill
    // dispatches and surface this kernel's counters in rocprof top-5.
    fused_qnn_kernel<<<BATCH * 2, 256, 0, stream>>>(
        x, ry_theta, crz_theta, fc1_w, fc1_b, fc2_w, fc2_b, out);
}